// Round 16
// baseline (128.675 us; speedup 1.0000x reference)
//
#include <hip/hip_runtime.h>
#include <hip/hip_bf16.h>
#include <stdint.h>

typedef __bf16 bf16_t;
typedef bf16_t bf16x4 __attribute__((ext_vector_type(4)));
typedef bf16_t bf16x8 __attribute__((ext_vector_type(8)));
typedef short s16x4 __attribute__((ext_vector_type(4)));
typedef int i32x4 __attribute__((ext_vector_type(4)));
typedef float f32x4 __attribute__((ext_vector_type(4)));
typedef unsigned int u32;
typedef u32 u32x4 __attribute__((ext_vector_type(4)));
typedef u32 u32x2 __attribute__((ext_vector_type(2)));

#define QMAXF 127.0f
#define CSC 0.18033688f   // 0.125 * log2(e): folded into Q at GEMM1 epilogue

// async global->LDS, 16B per lane. LDS dest is wave-uniform base + lane*16.
__device__ __forceinline__ void gl16(const void* g, void* l) {
  __builtin_amdgcn_global_load_lds(
      (__attribute__((address_space(1))) void*)(g),
      (__attribute__((address_space(3))) void*)(l), 16, 0, 0);
}

// ---------------- fused 3-tensor amax ----------------
__global__ __launch_bounds__(256) void amax3_kernel(const float* __restrict__ p0, int n0,
                                                    const float* __restrict__ p1, int n1,
                                                    const float* __restrict__ p2, int n2,
                                                    float* __restrict__ dst) {
  const float* p; int n; float* d; int b0, nb;
  if (blockIdx.x < 512)      { p = p0; n = n0; d = dst + 0; b0 = 0;   nb = 512; }
  else if (blockIdx.x < 768) { p = p1; n = n1; d = dst + 1; b0 = 512; nb = 256; }
  else                       { p = p2; n = n2; d = dst + 2; b0 = 768; nb = 128; }
  const int n4 = n >> 2;
  const int stride = nb * 256;
  float m = 0.f;
  for (int i = (blockIdx.x - b0) * 256 + threadIdx.x; i < n4; i += stride) {
    const f32x4 v = ((const f32x4*)p)[i];
    m = fmaxf(m, fmaxf(fmaxf(fabsf(v[0]), fabsf(v[1])), fmaxf(fabsf(v[2]), fabsf(v[3]))));
  }
#pragma unroll
  for (int dd = 1; dd < 64; dd <<= 1) m = fmaxf(m, __shfl_xor(m, dd));
  __shared__ float sm[4];
  if ((threadIdx.x & 63) == 0) sm[threadIdx.x >> 6] = m;
  __syncthreads();
  if (threadIdx.x == 0) {
    float mm = fmaxf(fmaxf(sm[0], sm[1]), fmaxf(sm[2], sm[3]));
    atomicMax((int*)d, __float_as_int(mm));  // valid: values >= 0
  }
}

// ---------------- int8 quantize: clip(round(x/s),-127,127) ----------------
__device__ __forceinline__ void quant_body(const float* __restrict__ p, int n,
                                           const float* __restrict__ amax,
                                           int8_t* __restrict__ q, int bid, int nb) {
  const float s = fmaxf(amax[0] / QMAXF, 1e-8f);
  const int n4 = n >> 2;
  const int stride = nb * 256;
  for (int i = bid * 256 + (int)threadIdx.x; i < n4; i += stride) {
    const f32x4 v = ((const f32x4*)p)[i];
    int r[4];
#pragma unroll
    for (int j = 0; j < 4; j++) {
      float t = rintf(v[j] / s);               // RNE == jnp.round
      t = fminf(127.f, fmaxf(-127.f, t));
      r[j] = (int)t;
    }
    ((uint32_t*)q)[i] = (uint32_t)(r[0] & 0xff) | ((uint32_t)(r[1] & 0xff) << 8) |
                        ((uint32_t)(r[2] & 0xff) << 16) | ((uint32_t)(r[3] & 0xff) << 24);
  }
}

__global__ __launch_bounds__(256) void quant3_kernel(const float* __restrict__ p0, int n0,
                                                     const float* __restrict__ p1, int n1,
                                                     const float* __restrict__ p2, int n2,
                                                     const float* __restrict__ amax,
                                                     int8_t* __restrict__ q0,
                                                     int8_t* __restrict__ q1,
                                                     int8_t* __restrict__ q2) {
  if (blockIdx.x < 512)      quant_body(p0, n0, amax + 0, q0, blockIdx.x, 512);
  else if (blockIdx.x < 768) quant_body(p1, n1, amax + 1, q1, blockIdx.x - 512, 256);
  else                       quant_body(p2, n2, amax + 2, q2, blockIdx.x - 768, 128);
}

// ---------------- bf16-input int8 quantize (for attention output) ----------------
__global__ __launch_bounds__(256) void quant_bf16_kernel(const u32* __restrict__ p,  // bf16x2 words
                                                         int n,                      // elements
                                                         const float* __restrict__ amax,
                                                         int8_t* __restrict__ q) {
  const float s = fmaxf(amax[0] / QMAXF, 1e-8f);
  const int n8 = n >> 3;
  const int stride = gridDim.x * blockDim.x;
  for (int i = blockIdx.x * blockDim.x + (int)threadIdx.x; i < n8; i += stride) {
    const u32x4 v = ((const u32x4*)p)[i];   // 8 bf16
    int r[8];
#pragma unroll
    for (int k = 0; k < 4; k++) {
      const float lo = __uint_as_float(v[k] << 16);
      const float hi = __uint_as_float(v[k] & 0xffff0000u);
      float t0 = fminf(127.f, fmaxf(-127.f, rintf(lo / s)));
      float t1 = fminf(127.f, fmaxf(-127.f, rintf(hi / s)));
      r[2 * k] = (int)t0; r[2 * k + 1] = (int)t1;
    }
    u32x2 o;
    o[0] = (u32)(r[0] & 0xff) | ((u32)(r[1] & 0xff) << 8) |
           ((u32)(r[2] & 0xff) << 16) | ((u32)(r[3] & 0xff) << 24);
    o[1] = (u32)(r[4] & 0xff) | ((u32)(r[5] & 0xff) << 8) |
           ((u32)(r[6] & 0xff) << 16) | ((u32)(r[7] & 0xff) << 24);
    ((u32x2*)q)[i] = o;
  }
}

// ---------------- int8 GEMM: out[M,N] = A[M,K] * Bw[N,K]^T, K=1024 ----------------
// Double-buffered staging (R9): stage(k+1) issued BEFORE compute(k), one barrier/K-step.
// MODE 0: dequant+bias; Q (pre-scaled by CSC), K -> bf16 [which][BH][T][D];
//         V -> bf16 V^T [BH][D][T]  (N=3072)
// MODE 1: dequant+bias, write fp32 row-major [M,1024]  (N=1024)
template <int MODE>
__global__ __launch_bounds__(256) void gemm_i8_kernel(
    const int8_t* __restrict__ A, const int8_t* __restrict__ Bw,
    const float* __restrict__ amaxA, const float* __restrict__ amaxB,
    const float* __restrict__ bias,
    bf16_t* __restrict__ qkv_out, bf16_t* __restrict__ vt_out, float* __restrict__ f_out) {
  constexpr int K = 1024;
  __shared__ int8_t As[2][8192];
  __shared__ int8_t Bs[2][8192];
  const int tid = threadIdx.x;
  const int lane = tid & 63;
  const int w = tid >> 6, wr = w >> 1, wc = w & 1;
  const int l15 = lane & 15, lg = lane >> 4;
  const int bm = blockIdx.y * 128, bn = blockIdx.x * 128;

  const int sr = tid >> 2;
  const int sc = (tid & 3) * 16;
  const int8_t* gA = A + (size_t)(bm + sr) * K + sc;
  const int8_t* gB = Bw + (size_t)(bn + sr) * K + sc;

  auto stage = [&](int k0, int buf) {
    gl16(gA + k0, As[buf] + tid * 16);
    gl16(gA + 64 * K + k0, As[buf] + 4096 + tid * 16);
    gl16(gB + k0, Bs[buf] + tid * 16);
    gl16(gB + 64 * K + k0, Bs[buf] + 4096 + tid * 16);
  };

  i32x4 acc[4][4] = {};

  stage(0, 0);
  __syncthreads();
  for (int ks = 0; ks < K / 64; ks++) {
    const int buf = ks & 1;
    if (ks + 1 < K / 64) stage((ks + 1) * 64, buf ^ 1);   // flies under compute
    i32x4 aF[4], bF[4];
#pragma unroll
    for (int m = 0; m < 4; m++)
      aF[m] = *(const i32x4*)(As[buf] + (wr * 64 + m * 16 + l15) * 64 + lg * 16);
#pragma unroll
    for (int n = 0; n < 4; n++)
      bF[n] = *(const i32x4*)(Bs[buf] + (wc * 64 + n * 16 + l15) * 64 + lg * 16);
#pragma unroll
    for (int m = 0; m < 4; m++)
#pragma unroll
      for (int n = 0; n < 4; n++)
        acc[m][n] = __builtin_amdgcn_mfma_i32_16x16x64_i8(aF[m], bF[n], acc[m][n], 0, 0, 0);
    __syncthreads();   // drains own vmcnt: next tile landed; all waves done with buf
  }

  const float sA = fmaxf(amaxA[0] / QMAXF, 1e-8f);
  const float sB = fmaxf(amaxB[0] / QMAXF, 1e-8f);
  const float s = sA * sB;

#pragma unroll
  for (int m = 0; m < 4; m++) {
#pragma unroll
    for (int n = 0; n < 4; n++) {
      const int c = bn + wc * 64 + n * 16 + l15;
      const float bs = bias[c];
      const int r0 = bm + wr * 64 + m * 16 + lg * 4;
      float vv[4];
#pragma unroll
      for (int reg = 0; reg < 4; reg++) vv[reg] = (float)acc[m][n][reg] * s + bs;
      if (MODE == 0) {
        const int which = c >> 10, hd = c & 1023;   // uniform over the 16-col fragment
        if (which < 2) {
          const float qs = (which == 0) ? CSC : 1.0f;   // fold softmax scale into Q
#pragma unroll
          for (int reg = 0; reg < 4; reg++) {
            const int r = r0 + reg;
            const int b = r >> 11, t = r & 2047;
            qkv_out[(size_t)which * (32u * 2048 * 64) +
                    (size_t)((((b << 4) + (hd >> 6)) * 2048 + t) << 6) + (hd & 63)] =
                (bf16_t)(vv[reg] * qs);
          }
        } else {
          // V^T [BH][D=64][T=2048], t contiguous within the 4 regs -> vector store
          const int b = r0 >> 11, t0 = r0 & 2047;
          const int h = hd >> 6, d = hd & 63;
          bf16x4 pk;
#pragma unroll
          for (int reg = 0; reg < 4; reg++) pk[reg] = (bf16_t)vv[reg];
          *(bf16x4*)(vt_out + ((size_t)((b << 4) + h) * 64 + d) * 2048 + t0) = pk;
        }
      } else {
#pragma unroll
        for (int reg = 0; reg < 4; reg++) f_out[(size_t)(r0 + reg) * 1024 + c] = vv[reg];
      }
    }
  }
}

// ---------------- causal flash attention: SHARED-KV dual supertile ----------------
// grid (32 bh, 16 pairs), block 256 = 4 waves x 16 q-rows per half.
// Block owns supertiles A=S (small) and B=31-S (big). ONE shared KV loop of
// nt = 32-S iters: each staged K/V tile feeds BOTH halves (A active while it<=S).
// Same MFMA half-iters as R8 (33/block, uniform); barrier/fence/stage count drops
// 33 -> 32-S (mean 24.5) and staging traffic HALVES, with unchanged LDS footprint
// (R14's failure mode avoided). Triple-buffer + counted vmcnt(4) exactly as R8.
// Zero-max softmax (log2 domain, Q pre-scaled by CSC); deferred row-sum; bf16 out.
__global__ __launch_bounds__(256, 2) void attn_kernel(
    const bf16_t* __restrict__ Qg, const bf16_t* __restrict__ Kg, const bf16_t* __restrict__ VTg,
    bf16_t* __restrict__ Out, float* __restrict__ amax_out) {
  const int bh = blockIdx.x;            // fastest-varying -> bh%8 pins XCD (L2 locality)
  const int pairi = blockIdx.y;         // 0..15
  const int tid = threadIdx.x, lane = tid & 63, w = tid >> 6;
  const int l15 = lane & 15, lg = lane >> 4;
  const int b = bh >> 4, h = bh & 15;

  const bf16_t* Qp = Qg + (size_t)bh * 2048 * 64;
  const char* Kbase = (const char*)(Kg + (size_t)bh * 2048 * 64);
  const char* Vbase = (const char*)(VTg + (size_t)bh * 64 * 2048);

  __shared__ __align__(16) bf16_t Kb[3][4096];   // [64 kv][64 d], swizzled, triple-buffered
  __shared__ __align__(16) bf16_t Vb[3][4096];   // [64 d][64 kv], swizzled, triple-buffered

  // waves 0,1 stage K (4x 1KB each); waves 2,3 stage V; swizzle via global source
  auto stage = [&](int kv0, int buf) {
#pragma unroll
    for (int i = 0; i < 4; i++) {
      const int o = ((w & 1) * 4 + i) * 1024 + lane * 16;
      const int row = o >> 7;
      const int sbc = (o & 127) ^ ((row & 7) << 4);
      if (w < 2)
        gl16(Kbase + (size_t)(kv0 + row) * 128 + sbc, (char*)Kb[buf] + o);
      else
        gl16(Vbase + (size_t)row * 4096 + (size_t)kv0 * 2 + sbc, (char*)Vb[buf] + o);
    }
  };

  const int SA = pairi;                 // small supertile (active for it <= SA)
  const int SB = 31 - pairi;            // big supertile (active every iter)
  const int nt = SB + 1;                // 17..32 shared KV iters
  const int qbA = SA * 64 + w * 16, qbB = SB * 64 + w * 16;
  const int qrowA = qbA + l15, qrowB = qbB + l15;

  bf16x8 qfA[2], qfB[2];
#pragma unroll
  for (int ks = 0; ks < 2; ks++) {
    qfA[ks] = *(const bf16x8*)(Qp + (size_t)(qbA + l15) * 64 + ks * 32 + lg * 8);
    qfB[ks] = *(const bf16x8*)(Qp + (size_t)(qbB + l15) * 64 + ks * 32 + lg * 8);
  }

  f32x4 accA[4] = {}, accB[4] = {};
  float lsumA = 0.f, lsumB = 0.f;

  stage(0, 0);
  stage(64, 1);                         // nt >= 17 always

  for (int it = 0; it < nt; ++it) {
    const int sl = it % 3;
    const int kv0 = it * 64;

    // own tile-it landed (tile it+1 stays in flight) -> barrier publishes all deposits
    if (it + 1 < nt) { asm volatile("s_waitcnt vmcnt(4)" ::: "memory"); }
    else             { asm volatile("s_waitcnt vmcnt(0)" ::: "memory"); }
    __builtin_amdgcn_sched_barrier(0);
    __builtin_amdgcn_s_barrier();        // raw: no drain, prefetches keep flying
    __builtin_amdgcn_sched_barrier(0);

    bf16x8 kF[4][2];
#pragma unroll
    for (int rf = 0; rf < 4; rf++)
#pragma unroll
      for (int ks = 0; ks < 2; ks++) {
        const int row = rf * 16 + l15;
        kF[rf][ks] = *(const bf16x8*)((const char*)Kb[sl] + row * 128 +
                                      ((ks * 64 + lg * 16) ^ ((row & 7) << 4)));
      }
    s16x4 vB[4][4];
#pragma unroll
    for (int cf = 0; cf < 4; cf++)
#pragma unroll
      for (int rf = 0; rf < 4; rf++) {
        const int row = cf * 16 + l15;
        vB[cf][rf] = *(const s16x4*)((const char*)Vb[sl] + row * 128 +
                                     ((rf * 32 + lg * 8) ^ ((row & 7) << 4)));
      }
    // prefetch tile it+2 into slot (it+2)%3 (readers of it-1 already past barrier(it))
    if (it + 2 < nt) stage(kv0 + 128, (it + 2) % 3);
    // fragments in VGPRs before compute (proven R8 ordering)
    asm volatile("s_waitcnt lgkmcnt(0)" ::: "memory");
    __builtin_amdgcn_sched_barrier(0);

    // half B QK first (independent chain, fills the MFMA pipe)
    f32x4 sfB[4] = {};
    __builtin_amdgcn_s_setprio(1);
#pragma unroll
    for (int rf = 0; rf < 4; rf++)
#pragma unroll
      for (int ks = 0; ks < 2; ks++)
        sfB[rf] = __builtin_amdgcn_mfma_f32_16x16x32_bf16(kF[rf][ks], qfB[ks], sfB[rf], 0, 0, 0);
    __builtin_amdgcn_s_setprio(0);

    // half A full chain (wave-uniform branch; same staged tile)
    if (it <= SA) {
      f32x4 sfA[4] = {};
      __builtin_amdgcn_s_setprio(1);
#pragma unroll
      for (int rf = 0; rf < 4; rf++)
#pragma unroll
        for (int ks = 0; ks < 2; ks++)
          sfA[rf] = __builtin_amdgcn_mfma_f32_16x16x32_bf16(kF[rf][ks], qfA[ks], sfA[rf], 0, 0, 0);
      __builtin_amdgcn_s_setprio(0);

      const bool maskA = (it == SA);
      float p[16];
#pragma unroll
      for (int rf = 0; rf < 4; rf++)
#pragma unroll
        for (int reg = 0; reg < 4; reg++) {
          float v = sfA[rf][reg];
          if (maskA && (kv0 + rf * 16 + lg * 4 + reg > qrowA)) v = -1e30f;
          p[rf * 4 + reg] = __builtin_amdgcn_exp2f(v);
        }
      float s01 = (p[0] + p[1]) + (p[2] + p[3]);
      float s23 = (p[4] + p[5]) + (p[6] + p[7]);
      float s45 = (p[8] + p[9]) + (p[10] + p[11]);
      float s67 = (p[12] + p[13]) + (p[14] + p[15]);
      lsumA += (s01 + s23) + (s45 + s67);

      s16x4 pa[4];
#pragma unroll
      for (int rf = 0; rf < 4; rf++) {
        bf16x4 t;
#pragma unroll
        for (int reg = 0; reg < 4; reg++) t[reg] = (bf16_t)p[rf * 4 + reg];
        pa[rf] = __builtin_bit_cast(s16x4, t);
      }
      __builtin_amdgcn_s_setprio(1);
#pragma unroll
      for (int cf = 0; cf < 4; cf++)
#pragma unroll
        for (int rf = 0; rf < 4; rf++)
          accA[cf] = __builtin_amdgcn_mfma_f32_16x16x16bf16_1k(pa[rf], vB[cf][rf], accA[cf], 0, 0, 0);
      __builtin_amdgcn_s_setprio(0);
    }

    // half B softmax + PV (always)
    {
      const bool maskB = (it == nt - 1);
      float p[16];
#pragma unroll
      for (int rf = 0; rf < 4; rf++)
#pragma unroll
        for (int reg = 0; reg < 4; reg++) {
          float v = sfB[rf][reg];
          if (maskB && (kv0 + rf * 16 + lg * 4 + reg > qrowB)) v = -1e30f;
          p[rf * 4 + reg] = __builtin_amdgcn_exp2f(v);
        }
      float s01 = (p[0] + p[1]) + (p[2] + p[3]);
      float s23 = (p[4] + p[5]) + (p[6] + p[7]);
      float s45 = (p[8] + p[9]) + (p[10] + p[11]);
      float s67 = (p[12] + p[13]) + (p[14] + p[15]);
      lsumB += (s01 + s23) + (s45 + s67);

      s16x4 pa[4];
#pragma unroll
      for (int rf = 0; rf < 4; rf++) {
        bf16x4 t;
#pragma unroll
        for (int reg = 0; reg < 4; reg++) t[reg] = (bf16_t)p[rf * 4 + reg];
        pa[rf] = __builtin_bit_cast(s16x4, t);
      }
      __builtin_amdgcn_s_setprio(1);
#pragma unroll
      for (int cf = 0; cf < 4; cf++)
#pragma unroll
        for (int rf = 0; rf < 4; rf++)
          accB[cf] = __builtin_amdgcn_mfma_f32_16x16x16bf16_1k(pa[rf], vB[cf][rf], accB[cf], 0, 0, 0);
      __builtin_amdgcn_s_setprio(0);
    }
  }

  // epilogues (registers + global only; no LDS dependence remains)
  float am = 0.f;
  {
    float ls = lsumA;
    ls += __shfl_xor(ls, 16);
    ls += __shfl_xor(ls, 32);
    const float inv = 1.0f / ls;
    float iq[4];
#pragma unroll
    for (int reg = 0; reg < 4; reg++) iq[reg] = __shfl(inv, lg * 4 + reg);
#pragma unroll
    for (int cf = 0; cf < 4; cf++)
#pragma unroll
      for (int reg = 0; reg < 4; reg++) {
        const float v = accA[cf][reg] * iq[reg];
        am = fmaxf(am, fabsf(v));
        const int t = qbA + lg * 4 + reg;
        Out[(size_t)(b * 2048 + t) * 1024 + h * 64 + cf * 16 + l15] = (bf16_t)v;
      }
  }
  {
    float ls = lsumB;
    ls += __shfl_xor(ls, 16);
    ls += __shfl_xor(ls, 32);
    const float inv = 1.0f / ls;
    float iq[4];
#pragma unroll
    for (int reg = 0; reg < 4; reg++) iq[reg] = __shfl(inv, lg * 4 + reg);
#pragma unroll
    for (int cf = 0; cf < 4; cf++)
#pragma unroll
      for (int reg = 0; reg < 4; reg++) {
        const float v = accB[cf][reg] * iq[reg];
        am = fmaxf(am, fabsf(v));
        const int t = qbB + lg * 4 + reg;
        Out[(size_t)(b * 2048 + t) * 1024 + h * 64 + cf * 16 + l15] = (bf16_t)v;
      }
  }

#pragma unroll
  for (int dd = 1; dd < 64; dd <<= 1) am = fmaxf(am, __shfl_xor(am, dd));
  if (lane == 0) atomicMax((int*)amax_out, __float_as_int(am));
}

// ---------------- host ----------------
extern "C" void kernel_launch(void* const* d_in, const int* in_sizes, int n_in,
                              void* d_out, int out_size, void* d_ws, size_t ws_size,
                              hipStream_t stream) {
  const float* x = (const float*)d_in[0];
  const float* Wqkv = (const float*)d_in[1];
  const float* bqkv = (const float*)d_in[2];
  const float* Wproj = (const float*)d_in[3];
  const float* bproj = (const float*)d_in[4];
  float* out = (float*)d_out;

  char* ws = (char*)d_ws;
  float* amax = (float*)ws;                                  // 4 floats
  int8_t* xq = (int8_t*)(ws + 256);                          // 4 MB
  int8_t* wqq = xq + (size_t)4096 * 1024;                    // 3 MB
  int8_t* wpq = wqq + (size_t)3072 * 1024;                   // 1 MB
  bf16_t* qkv = (bf16_t*)(ws + 8388864);                     // Q | K | VT, 3 x 8 MB bf16
  bf16_t* Q = qkv;
  bf16_t* Kk = qkv + (size_t)32 * 2048 * 64;
  bf16_t* VT = qkv + (size_t)2 * 32 * 2048 * 64;             // [BH][D][T]
  bf16_t* aout = (bf16_t*)(ws + 33554688);                   // 8 MB bf16 attn out
  int8_t* outq = (int8_t*)(ws + 50331904);                   // 4 MB

  hipMemsetAsync(amax, 0, 16, stream);
  amax3_kernel<<<896, 256, 0, stream>>>(x, 4194304, Wqkv, 3145728, Wproj, 1048576, amax);
  quant3_kernel<<<896, 256, 0, stream>>>(x, 4194304, Wqkv, 3145728, Wproj, 1048576, amax,
                                         xq, wqq, wpq);
  gemm_i8_kernel<0><<<dim3(24, 32), 256, 0, stream>>>(xq, wqq, amax + 0, amax + 1, bqkv,
                                                      qkv, VT, nullptr);
  attn_kernel<<<dim3(32, 16), 256, 0, stream>>>(Q, Kk, VT, aout, amax + 3);
  quant_bf16_kernel<<<512, 256, 0, stream>>>((const u32*)aout, 4194304, amax + 3, outq);
  gemm_i8_kernel<1><<<dim3(8, 32), 256, 0, stream>>>(outq, wpq, amax + 3, amax + 2, bproj,
                                                     nullptr, nullptr, out);
}

// Round 17
// 126.283 us; speedup vs baseline: 1.0189x; 1.0189x over previous
//
#include <hip/hip_runtime.h>
#include <hip/hip_bf16.h>
#include <stdint.h>

typedef __bf16 bf16_t;
typedef bf16_t bf16x4 __attribute__((ext_vector_type(4)));
typedef bf16_t bf16x8 __attribute__((ext_vector_type(8)));
typedef short s16x4 __attribute__((ext_vector_type(4)));
typedef int i32x4 __attribute__((ext_vector_type(4)));
typedef float f32x4 __attribute__((ext_vector_type(4)));
typedef unsigned int u32;
typedef u32 u32x4 __attribute__((ext_vector_type(4)));
typedef u32 u32x2 __attribute__((ext_vector_type(2)));

#define QMAXF 127.0f
#define CSC 0.18033688f   // 0.125 * log2(e): folded into Q at GEMM1 epilogue

// async global->LDS, 16B per lane. LDS dest is wave-uniform base + lane*16.
__device__ __forceinline__ void gl16(const void* g, void* l) {
  __builtin_amdgcn_global_load_lds(
      (__attribute__((address_space(1))) void*)(g),
      (__attribute__((address_space(3))) void*)(l), 16, 0, 0);
}

// ---------------- fused 3-tensor amax ----------------
__global__ __launch_bounds__(256) void amax3_kernel(const float* __restrict__ p0, int n0,
                                                    const float* __restrict__ p1, int n1,
                                                    const float* __restrict__ p2, int n2,
                                                    float* __restrict__ dst) {
  const float* p; int n; float* d; int b0, nb;
  if (blockIdx.x < 512)      { p = p0; n = n0; d = dst + 0; b0 = 0;   nb = 512; }
  else if (blockIdx.x < 768) { p = p1; n = n1; d = dst + 1; b0 = 512; nb = 256; }
  else                       { p = p2; n = n2; d = dst + 2; b0 = 768; nb = 128; }
  const int n4 = n >> 2;
  const int stride = nb * 256;
  float m = 0.f;
  for (int i = (blockIdx.x - b0) * 256 + threadIdx.x; i < n4; i += stride) {
    const f32x4 v = ((const f32x4*)p)[i];
    m = fmaxf(m, fmaxf(fmaxf(fabsf(v[0]), fabsf(v[1])), fmaxf(fabsf(v[2]), fabsf(v[3]))));
  }
#pragma unroll
  for (int dd = 1; dd < 64; dd <<= 1) m = fmaxf(m, __shfl_xor(m, dd));
  __shared__ float sm[4];
  if ((threadIdx.x & 63) == 0) sm[threadIdx.x >> 6] = m;
  __syncthreads();
  if (threadIdx.x == 0) {
    float mm = fmaxf(fmaxf(sm[0], sm[1]), fmaxf(sm[2], sm[3]));
    atomicMax((int*)d, __float_as_int(mm));  // valid: values >= 0
  }
}

// ---------------- int8 quantize: clip(round(x/s),-127,127) ----------------
__device__ __forceinline__ void quant_body(const float* __restrict__ p, int n,
                                           const float* __restrict__ amax,
                                           int8_t* __restrict__ q, int bid, int nb) {
  const float s = fmaxf(amax[0] / QMAXF, 1e-8f);
  const int n4 = n >> 2;
  const int stride = nb * 256;
  for (int i = bid * 256 + (int)threadIdx.x; i < n4; i += stride) {
    const f32x4 v = ((const f32x4*)p)[i];
    int r[4];
#pragma unroll
    for (int j = 0; j < 4; j++) {
      float t = rintf(v[j] / s);               // RNE == jnp.round
      t = fminf(127.f, fmaxf(-127.f, t));
      r[j] = (int)t;
    }
    ((uint32_t*)q)[i] = (uint32_t)(r[0] & 0xff) | ((uint32_t)(r[1] & 0xff) << 8) |
                        ((uint32_t)(r[2] & 0xff) << 16) | ((uint32_t)(r[3] & 0xff) << 24);
  }
}

__global__ __launch_bounds__(256) void quant3_kernel(const float* __restrict__ p0, int n0,
                                                     const float* __restrict__ p1, int n1,
                                                     const float* __restrict__ p2, int n2,
                                                     const float* __restrict__ amax,
                                                     int8_t* __restrict__ q0,
                                                     int8_t* __restrict__ q1,
                                                     int8_t* __restrict__ q2) {
  if (blockIdx.x < 512)      quant_body(p0, n0, amax + 0, q0, blockIdx.x, 512);
  else if (blockIdx.x < 768) quant_body(p1, n1, amax + 1, q1, blockIdx.x - 512, 256);
  else                       quant_body(p2, n2, amax + 2, q2, blockIdx.x - 768, 128);
}

// ---------------- bf16-input int8 quantize (for attention output) ----------------
__global__ __launch_bounds__(256) void quant_bf16_kernel(const u32* __restrict__ p,  // bf16x2 words
                                                         int n,                      // elements
                                                         const float* __restrict__ amax,
                                                         int8_t* __restrict__ q) {
  const float s = fmaxf(amax[0] / QMAXF, 1e-8f);
  const int n8 = n >> 3;
  const int stride = gridDim.x * blockDim.x;
  for (int i = blockIdx.x * blockDim.x + (int)threadIdx.x; i < n8; i += stride) {
    const u32x4 v = ((const u32x4*)p)[i];   // 8 bf16
    int r[8];
#pragma unroll
    for (int k = 0; k < 4; k++) {
      const float lo = __uint_as_float(v[k] << 16);
      const float hi = __uint_as_float(v[k] & 0xffff0000u);
      float t0 = fminf(127.f, fmaxf(-127.f, rintf(lo / s)));
      float t1 = fminf(127.f, fmaxf(-127.f, rintf(hi / s)));
      r[2 * k] = (int)t0; r[2 * k + 1] = (int)t1;
    }
    u32x2 o;
    o[0] = (u32)(r[0] & 0xff) | ((u32)(r[1] & 0xff) << 8) |
           ((u32)(r[2] & 0xff) << 16) | ((u32)(r[3] & 0xff) << 24);
    o[1] = (u32)(r[4] & 0xff) | ((u32)(r[5] & 0xff) << 8) |
           ((u32)(r[6] & 0xff) << 16) | ((u32)(r[7] & 0xff) << 24);
    ((u32x2*)q)[i] = o;
  }
}

// ---------------- int8 GEMM: out[M,N] = A[M,K] * Bw[N,K]^T, K=1024 ----------------
// Double-buffered staging (R9, measured win): stage(k+1) issued BEFORE compute(k),
// one barrier per K-step.
// MODE 0: dequant+bias; Q (pre-scaled by CSC), K -> bf16 [which][BH][T][D];
//         V -> bf16 V^T [BH][D][T]  (N=3072)
// MODE 1: dequant+bias, write fp32 row-major [M,1024]  (N=1024)
template <int MODE>
__global__ __launch_bounds__(256) void gemm_i8_kernel(
    const int8_t* __restrict__ A, const int8_t* __restrict__ Bw,
    const float* __restrict__ amaxA, const float* __restrict__ amaxB,
    const float* __restrict__ bias,
    bf16_t* __restrict__ qkv_out, bf16_t* __restrict__ vt_out, float* __restrict__ f_out) {
  constexpr int K = 1024;
  __shared__ int8_t As[2][8192];
  __shared__ int8_t Bs[2][8192];
  const int tid = threadIdx.x;
  const int lane = tid & 63;
  const int w = tid >> 6, wr = w >> 1, wc = w & 1;
  const int l15 = lane & 15, lg = lane >> 4;
  const int bm = blockIdx.y * 128, bn = blockIdx.x * 128;

  const int sr = tid >> 2;
  const int sc = (tid & 3) * 16;
  const int8_t* gA = A + (size_t)(bm + sr) * K + sc;
  const int8_t* gB = Bw + (size_t)(bn + sr) * K + sc;

  auto stage = [&](int k0, int buf) {
    gl16(gA + k0, As[buf] + tid * 16);
    gl16(gA + 64 * K + k0, As[buf] + 4096 + tid * 16);
    gl16(gB + k0, Bs[buf] + tid * 16);
    gl16(gB + 64 * K + k0, Bs[buf] + 4096 + tid * 16);
  };

  i32x4 acc[4][4] = {};

  stage(0, 0);
  __syncthreads();
  for (int ks = 0; ks < K / 64; ks++) {
    const int buf = ks & 1;
    if (ks + 1 < K / 64) stage((ks + 1) * 64, buf ^ 1);   // flies under compute
    i32x4 aF[4], bF[4];
#pragma unroll
    for (int m = 0; m < 4; m++)
      aF[m] = *(const i32x4*)(As[buf] + (wr * 64 + m * 16 + l15) * 64 + lg * 16);
#pragma unroll
    for (int n = 0; n < 4; n++)
      bF[n] = *(const i32x4*)(Bs[buf] + (wc * 64 + n * 16 + l15) * 64 + lg * 16);
#pragma unroll
    for (int m = 0; m < 4; m++)
#pragma unroll
      for (int n = 0; n < 4; n++)
        acc[m][n] = __builtin_amdgcn_mfma_i32_16x16x64_i8(aF[m], bF[n], acc[m][n], 0, 0, 0);
    __syncthreads();   // drains own vmcnt: next tile landed; all waves done with buf
  }

  const float sA = fmaxf(amaxA[0] / QMAXF, 1e-8f);
  const float sB = fmaxf(amaxB[0] / QMAXF, 1e-8f);
  const float s = sA * sB;

#pragma unroll
  for (int m = 0; m < 4; m++) {
#pragma unroll
    for (int n = 0; n < 4; n++) {
      const int c = bn + wc * 64 + n * 16 + l15;
      const float bs = bias[c];
      const int r0 = bm + wr * 64 + m * 16 + lg * 4;
      float vv[4];
#pragma unroll
      for (int reg = 0; reg < 4; reg++) vv[reg] = (float)acc[m][n][reg] * s + bs;
      if (MODE == 0) {
        const int which = c >> 10, hd = c & 1023;   // uniform over the 16-col fragment
        if (which < 2) {
          const float qs = (which == 0) ? CSC : 1.0f;   // fold softmax scale into Q
#pragma unroll
          for (int reg = 0; reg < 4; reg++) {
            const int r = r0 + reg;
            const int b = r >> 11, t = r & 2047;
            qkv_out[(size_t)which * (32u * 2048 * 64) +
                    (size_t)((((b << 4) + (hd >> 6)) * 2048 + t) << 6) + (hd & 63)] =
                (bf16_t)(vv[reg] * qs);
          }
        } else {
          // V^T [BH][D=64][T=2048], t contiguous within the 4 regs -> vector store
          const int b = r0 >> 11, t0 = r0 & 2047;
          const int h = hd >> 6, d = hd & 63;
          bf16x4 pk;
#pragma unroll
          for (int reg = 0; reg < 4; reg++) pk[reg] = (bf16_t)vv[reg];
          *(bf16x4*)(vt_out + ((size_t)((b << 4) + h) * 64 + d) * 2048 + t0) = pk;
        }
      } else {
#pragma unroll
        for (int reg = 0; reg < 4; reg++) f_out[(size_t)(r0 + reg) * 1024 + c] = vv[reg];
      }
    }
  }
}

// ---------------- causal flash attention (R8 structure, best measured: 57.3 us) ----------------
// grid (32 bh, 16 pairs), block 256 = 4 waves x 16 q-rows (64-row supertile).
// Block handles supertiles {S, 31-S} sequentially: EVERY block exactly 33 KV-iters.
// Counted-vmcnt triple-buffer: no vmcnt(0) drain in main loop.
// Exact R8 ordering (load-bearing, verified by R9 A/B): barrier -> read kF -> read vB ->
// stage(it+2) -> lgkmcnt(0) fence -> QK MFMA.
// ZERO-MAX softmax (log2 domain, Q pre-scaled by CSC): p = exp2(a), no running max,
// no cross-lane ops in loop; deferred row-sum. Output bf16.
// Survived 7 perturbation classes (occupancy, sync geometry, memory path, tile size,
// amortization) — converged local optimum.
__global__ __launch_bounds__(256, 2) void attn_kernel(
    const bf16_t* __restrict__ Qg, const bf16_t* __restrict__ Kg, const bf16_t* __restrict__ VTg,
    bf16_t* __restrict__ Out, float* __restrict__ amax_out) {
  const int bh = blockIdx.x;            // fastest-varying -> bh%8 pins XCD (L2 locality)
  const int pairi = blockIdx.y;         // 0..15
  const int tid = threadIdx.x, lane = tid & 63, w = tid >> 6;
  const int l15 = lane & 15, lg = lane >> 4;
  const int b = bh >> 4, h = bh & 15;

  const bf16_t* Qp = Qg + (size_t)bh * 2048 * 64;
  const char* Kbase = (const char*)(Kg + (size_t)bh * 2048 * 64);
  const char* Vbase = (const char*)(VTg + (size_t)bh * 64 * 2048);

  __shared__ __align__(16) bf16_t Kb[3][4096];   // [64 kv][64 d], swizzled, triple-buffered
  __shared__ __align__(16) bf16_t Vb[3][4096];   // [64 d][64 kv], swizzled, triple-buffered

  // waves 0,1 stage K (4x 1KB each); waves 2,3 stage V; swizzle via global source
  auto stage = [&](int kv0, int buf) {
#pragma unroll
    for (int i = 0; i < 4; i++) {
      const int o = ((w & 1) * 4 + i) * 1024 + lane * 16;
      const int row = o >> 7;
      const int sbc = (o & 127) ^ ((row & 7) << 4);
      if (w < 2)
        gl16(Kbase + (size_t)(kv0 + row) * 128 + sbc, (char*)Kb[buf] + o);
      else
        gl16(Vbase + (size_t)row * 4096 + (size_t)kv0 * 2 + sbc, (char*)Vb[buf] + o);
    }
  };

  float am = 0.f;
  for (int half = 0; half < 2; ++half) {
    const int S = half ? (31 - pairi) : pairi;
    const int qb = S * 64 + w * 16;     // this wave's 16 q-rows
    const int nt = S + 1;
    const int qrow = qb + l15;

    bf16x8 qf[2];
#pragma unroll
    for (int ks = 0; ks < 2; ks++)
      qf[ks] = *(const bf16x8*)(Qp + (size_t)(qb + l15) * 64 + ks * 32 + lg * 8);

    f32x4 acc[4] = {};
    float lsum = 0.f;

    stage(0, 0);
    if (nt > 1) stage(64, 1);

    for (int it = 0; it < nt; ++it) {
      const int sl = it % 3;
      const int kv0 = it * 64;

      // own tile-it landed (tile it+1 stays in flight) -> barrier publishes all deposits
      if (it + 1 < nt) { asm volatile("s_waitcnt vmcnt(4)" ::: "memory"); }
      else             { asm volatile("s_waitcnt vmcnt(0)" ::: "memory"); }
      __builtin_amdgcn_sched_barrier(0);
      __builtin_amdgcn_s_barrier();      // raw: no drain, prefetches keep flying
      __builtin_amdgcn_sched_barrier(0);

      bf16x8 kF[4][2];
#pragma unroll
      for (int rf = 0; rf < 4; rf++)
#pragma unroll
        for (int ks = 0; ks < 2; ks++) {
          const int row = rf * 16 + l15;
          kF[rf][ks] = *(const bf16x8*)((const char*)Kb[sl] + row * 128 +
                                        ((ks * 64 + lg * 16) ^ ((row & 7) << 4)));
        }
      s16x4 vB[4][4];
#pragma unroll
      for (int cf = 0; cf < 4; cf++)
#pragma unroll
        for (int rf = 0; rf < 4; rf++) {
          const int row = cf * 16 + l15;
          vB[cf][rf] = *(const s16x4*)((const char*)Vb[sl] + row * 128 +
                                       ((rf * 32 + lg * 8) ^ ((row & 7) << 4)));
        }
      // prefetch tile it+2 into slot (it+2)%3 (readers of it-1 already past barrier(it))
      if (it + 2 < nt) stage(kv0 + 128, (it + 2) % 3);
      // fragments in VGPRs before compute
      asm volatile("s_waitcnt lgkmcnt(0)" ::: "memory");
      __builtin_amdgcn_sched_barrier(0);

      f32x4 sfT[4] = {};
      __builtin_amdgcn_s_setprio(1);
#pragma unroll
      for (int rf = 0; rf < 4; rf++)
#pragma unroll
        for (int ks = 0; ks < 2; ks++)
          sfT[rf] = __builtin_amdgcn_mfma_f32_16x16x32_bf16(kF[rf][ks], qf[ks], sfT[rf], 0, 0, 0);
      __builtin_amdgcn_s_setprio(0);

      // zero-max softmax (log2 domain; Q pre-scaled): p = exp2(a), no cross-lane ops
      const bool need_mask = (it == nt - 1);
      float p[16];
#pragma unroll
      for (int rf = 0; rf < 4; rf++)
#pragma unroll
        for (int reg = 0; reg < 4; reg++) {
          float v = sfT[rf][reg];
          if (need_mask && (kv0 + rf * 16 + lg * 4 + reg > qrow)) v = -1e30f;
          p[rf * 4 + reg] = __builtin_amdgcn_exp2f(v);
        }
      // tree-sum of own 16 p's -> per-lane partial (cross-lane deferred to epilogue)
      float s01 = (p[0] + p[1]) + (p[2] + p[3]);
      float s23 = (p[4] + p[5]) + (p[6] + p[7]);
      float s45 = (p[8] + p[9]) + (p[10] + p[11]);
      float s67 = (p[12] + p[13]) + (p[14] + p[15]);
      lsum += (s01 + s23) + (s45 + s67);

      // p -> bf16 A-frags, feed PV directly (no LDS roundtrip)
      s16x4 pa[4];
#pragma unroll
      for (int rf = 0; rf < 4; rf++) {
        bf16x4 t;
#pragma unroll
        for (int reg = 0; reg < 4; reg++) t[reg] = (bf16_t)p[rf * 4 + reg];
        pa[rf] = __builtin_bit_cast(s16x4, t);
      }
      __builtin_amdgcn_s_setprio(1);
#pragma unroll
      for (int cf = 0; cf < 4; cf++)
#pragma unroll
        for (int rf = 0; rf < 4; rf++)
          acc[cf] = __builtin_amdgcn_mfma_f32_16x16x16bf16_1k(pa[rf], vB[cf][rf], acc[cf], 0, 0, 0);
      __builtin_amdgcn_s_setprio(0);
    }

    // row-sum: lane l15 holds partial for row qb+l15; reduce across lg groups
    lsum += __shfl_xor(lsum, 16);
    lsum += __shfl_xor(lsum, 32);
    const float inv = 1.0f / lsum;
    float iq[4];
#pragma unroll
    for (int reg = 0; reg < 4; reg++) iq[reg] = __shfl(inv, lg * 4 + reg);
#pragma unroll
    for (int cf = 0; cf < 4; cf++)
#pragma unroll
      for (int reg = 0; reg < 4; reg++) {
        const float v = acc[cf][reg] * iq[reg];
        am = fmaxf(am, fabsf(v));
        const int t = qb + lg * 4 + reg;
        Out[(size_t)(b * 2048 + t) * 1024 + h * 64 + cf * 16 + l15] = (bf16_t)v;
      }

    __syncthreads();   // full drain: protect buffer slots across the half boundary
  }

#pragma unroll
  for (int dd = 1; dd < 64; dd <<= 1) am = fmaxf(am, __shfl_xor(am, dd));
  if (lane == 0) atomicMax((int*)amax_out, __float_as_int(am));
}

// ---------------- host ----------------
extern "C" void kernel_launch(void* const* d_in, const int* in_sizes, int n_in,
                              void* d_out, int out_size, void* d_ws, size_t ws_size,
                              hipStream_t stream) {
  const float* x = (const float*)d_in[0];
  const float* Wqkv = (const float*)d_in[1];
  const float* bqkv = (const float*)d_in[2];
  const float* Wproj = (const float*)d_in[3];
  const float* bproj = (const float*)d_in[4];
  float* out = (float*)d_out;

  char* ws = (char*)d_ws;
  float* amax = (float*)ws;                                  // 4 floats
  int8_t* xq = (int8_t*)(ws + 256);                          // 4 MB
  int8_t* wqq = xq + (size_t)4096 * 1024;                    // 3 MB
  int8_t* wpq = wqq + (size_t)3072 * 1024;                   // 1 MB
  bf16_t* qkv = (bf16_t*)(ws + 8388864);                     // Q | K | VT, 3 x 8 MB bf16
  bf16_t* Q = qkv;
  bf16_t* Kk = qkv + (size_t)32 * 2048 * 64;
  bf16_t* VT = qkv + (size_t)2 * 32 * 2048 * 64;             // [BH][D][T]
  bf16_t* aout = (bf16_t*)(ws + 33554688);                   // 8 MB bf16 attn out
  int8_t* outq = (int8_t*)(ws + 50331904);                   // 4 MB

  hipMemsetAsync(amax, 0, 16, stream);
  amax3_kernel<<<896, 256, 0, stream>>>(x, 4194304, Wqkv, 3145728, Wproj, 1048576, amax);
  quant3_kernel<<<896, 256, 0, stream>>>(x, 4194304, Wqkv, 3145728, Wproj, 1048576, amax,
                                         xq, wqq, wpq);
  gemm_i8_kernel<0><<<dim3(24, 32), 256, 0, stream>>>(xq, wqq, amax + 0, amax + 1, bqkv,
                                                      qkv, VT, nullptr);
  attn_kernel<<<dim3(32, 16), 256, 0, stream>>>(Q, Kk, VT, aout, amax + 3);
  quant_bf16_kernel<<<512, 256, 0, stream>>>((const u32*)aout, 4194304, amax + 3, outq);
  gemm_i8_kernel<1><<<dim3(8, 32), 256, 0, stream>>>(outq, wpq, amax + 3, amax + 2, bproj,
                                                     nullptr, nullptr, out);
}

// Round 18
// 124.882 us; speedup vs baseline: 1.0304x; 1.0112x over previous
//
#include <hip/hip_runtime.h>
#include <hip/hip_bf16.h>
#include <stdint.h>

typedef __bf16 bf16_t;
typedef bf16_t bf16x4 __attribute__((ext_vector_type(4)));
typedef bf16_t bf16x8 __attribute__((ext_vector_type(8)));
typedef short s16x4 __attribute__((ext_vector_type(4)));
typedef int i32x4 __attribute__((ext_vector_type(4)));
typedef float f32x4 __attribute__((ext_vector_type(4)));
typedef unsigned int u32;
typedef u32 u32x4 __attribute__((ext_vector_type(4)));
typedef u32 u32x2 __attribute__((ext_vector_type(2)));

#define QMAXF 127.0f
#define CSC 0.18033688f   // 0.125 * log2(e): folded into Q at GEMM1 epilogue

// async global->LDS, 16B per lane. LDS dest is wave-uniform base + lane*16.
__device__ __forceinline__ void gl16(const void* g, void* l) {
  __builtin_amdgcn_global_load_lds(
      (__attribute__((address_space(1))) void*)(g),
      (__attribute__((address_space(3))) void*)(l), 16, 0, 0);
}

// ---------------- fused 3-tensor amax ----------------
__global__ __launch_bounds__(256) void amax3_kernel(const float* __restrict__ p0, int n0,
                                                    const float* __restrict__ p1, int n1,
                                                    const float* __restrict__ p2, int n2,
                                                    float* __restrict__ dst) {
  const float* p; int n; float* d; int b0, nb;
  if (blockIdx.x < 512)      { p = p0; n = n0; d = dst + 0; b0 = 0;   nb = 512; }
  else if (blockIdx.x < 768) { p = p1; n = n1; d = dst + 1; b0 = 512; nb = 256; }
  else                       { p = p2; n = n2; d = dst + 2; b0 = 768; nb = 128; }
  const int n4 = n >> 2;
  const int stride = nb * 256;
  float m = 0.f;
  for (int i = (blockIdx.x - b0) * 256 + threadIdx.x; i < n4; i += stride) {
    const f32x4 v = ((const f32x4*)p)[i];
    m = fmaxf(m, fmaxf(fmaxf(fabsf(v[0]), fabsf(v[1])), fmaxf(fabsf(v[2]), fabsf(v[3]))));
  }
#pragma unroll
  for (int dd = 1; dd < 64; dd <<= 1) m = fmaxf(m, __shfl_xor(m, dd));
  __shared__ float sm[4];
  if ((threadIdx.x & 63) == 0) sm[threadIdx.x >> 6] = m;
  __syncthreads();
  if (threadIdx.x == 0) {
    float mm = fmaxf(fmaxf(sm[0], sm[1]), fmaxf(sm[2], sm[3]));
    atomicMax((int*)d, __float_as_int(mm));  // valid: values >= 0
  }
}

// ---------------- int8 quantize: clip(round(x/s),-127,127) ----------------
__device__ __forceinline__ void quant_body(const float* __restrict__ p, int n,
                                           const float* __restrict__ amax,
                                           int8_t* __restrict__ q, int bid, int nb) {
  const float s = fmaxf(amax[0] / QMAXF, 1e-8f);
  const int n4 = n >> 2;
  const int stride = nb * 256;
  for (int i = bid * 256 + (int)threadIdx.x; i < n4; i += stride) {
    const f32x4 v = ((const f32x4*)p)[i];
    int r[4];
#pragma unroll
    for (int j = 0; j < 4; j++) {
      float t = rintf(v[j] / s);               // RNE == jnp.round
      t = fminf(127.f, fmaxf(-127.f, t));
      r[j] = (int)t;
    }
    ((uint32_t*)q)[i] = (uint32_t)(r[0] & 0xff) | ((uint32_t)(r[1] & 0xff) << 8) |
                        ((uint32_t)(r[2] & 0xff) << 16) | ((uint32_t)(r[3] & 0xff) << 24);
  }
}

__global__ __launch_bounds__(256) void quant3_kernel(const float* __restrict__ p0, int n0,
                                                     const float* __restrict__ p1, int n1,
                                                     const float* __restrict__ p2, int n2,
                                                     const float* __restrict__ amax,
                                                     int8_t* __restrict__ q0,
                                                     int8_t* __restrict__ q1,
                                                     int8_t* __restrict__ q2) {
  if (blockIdx.x < 512)      quant_body(p0, n0, amax + 0, q0, blockIdx.x, 512);
  else if (blockIdx.x < 768) quant_body(p1, n1, amax + 1, q1, blockIdx.x - 512, 256);
  else                       quant_body(p2, n2, amax + 2, q2, blockIdx.x - 768, 128);
}

// ---------------- bf16-input int8 quantize (for attention output) ----------------
__global__ __launch_bounds__(256) void quant_bf16_kernel(const u32* __restrict__ p,  // bf16x2 words
                                                         int n,                      // elements
                                                         const float* __restrict__ amax,
                                                         int8_t* __restrict__ q) {
  const float s = fmaxf(amax[0] / QMAXF, 1e-8f);
  const int n8 = n >> 3;
  const int stride = gridDim.x * blockDim.x;
  for (int i = blockIdx.x * blockDim.x + (int)threadIdx.x; i < n8; i += stride) {
    const u32x4 v = ((const u32x4*)p)[i];   // 8 bf16
    int r[8];
#pragma unroll
    for (int k = 0; k < 4; k++) {
      const float lo = __uint_as_float(v[k] << 16);
      const float hi = __uint_as_float(v[k] & 0xffff0000u);
      float t0 = fminf(127.f, fmaxf(-127.f, rintf(lo / s)));
      float t1 = fminf(127.f, fmaxf(-127.f, rintf(hi / s)));
      r[2 * k] = (int)t0; r[2 * k + 1] = (int)t1;
    }
    u32x2 o;
    o[0] = (u32)(r[0] & 0xff) | ((u32)(r[1] & 0xff) << 8) |
           ((u32)(r[2] & 0xff) << 16) | ((u32)(r[3] & 0xff) << 24);
    o[1] = (u32)(r[4] & 0xff) | ((u32)(r[5] & 0xff) << 8) |
           ((u32)(r[6] & 0xff) << 16) | ((u32)(r[7] & 0xff) << 24);
    ((u32x2*)q)[i] = o;
  }
}

// ---------------- int8 GEMM (QKV): 128x128 tile, K=1024, dbuf 2-phase, 3 blocks/CU ----------------
// dequant+bias; Q (pre-scaled by CSC), K -> bf16 [which][BH][T][D]; V -> bf16 V^T [BH][D][T]
__global__ __launch_bounds__(256) void gemm_qkv_kernel(
    const int8_t* __restrict__ A, const int8_t* __restrict__ Bw,
    const float* __restrict__ amaxA, const float* __restrict__ amaxB,
    const float* __restrict__ bias,
    bf16_t* __restrict__ qkv_out, bf16_t* __restrict__ vt_out) {
  constexpr int K = 1024;
  __shared__ int8_t As[2][8192];
  __shared__ int8_t Bs[2][8192];
  const int tid = threadIdx.x;
  const int lane = tid & 63;
  const int w = tid >> 6, wr = w >> 1, wc = w & 1;
  const int l15 = lane & 15, lg = lane >> 4;
  const int bm = blockIdx.y * 128, bn = blockIdx.x * 128;

  const int sr = tid >> 2;
  const int sc = (tid & 3) * 16;
  const int8_t* gA = A + (size_t)(bm + sr) * K + sc;
  const int8_t* gB = Bw + (size_t)(bn + sr) * K + sc;

  auto stage = [&](int k0, int buf) {
    gl16(gA + k0, As[buf] + tid * 16);
    gl16(gA + 64 * K + k0, As[buf] + 4096 + tid * 16);
    gl16(gB + k0, Bs[buf] + tid * 16);
    gl16(gB + 64 * K + k0, Bs[buf] + 4096 + tid * 16);
  };

  i32x4 acc[4][4] = {};

  stage(0, 0);
  __syncthreads();
  for (int ks = 0; ks < K / 64; ks++) {
    const int buf = ks & 1;
    if (ks + 1 < K / 64) stage((ks + 1) * 64, buf ^ 1);   // flies under compute
    i32x4 aF[4], bF[4];
#pragma unroll
    for (int m = 0; m < 4; m++)
      aF[m] = *(const i32x4*)(As[buf] + (wr * 64 + m * 16 + l15) * 64 + lg * 16);
#pragma unroll
    for (int n = 0; n < 4; n++)
      bF[n] = *(const i32x4*)(Bs[buf] + (wc * 64 + n * 16 + l15) * 64 + lg * 16);
#pragma unroll
    for (int m = 0; m < 4; m++)
#pragma unroll
      for (int n = 0; n < 4; n++)
        acc[m][n] = __builtin_amdgcn_mfma_i32_16x16x64_i8(aF[m], bF[n], acc[m][n], 0, 0, 0);
    __syncthreads();   // drains own vmcnt: next tile landed; all waves done with buf
  }

  const float sA = fmaxf(amaxA[0] / QMAXF, 1e-8f);
  const float sB = fmaxf(amaxB[0] / QMAXF, 1e-8f);
  const float s = sA * sB;

#pragma unroll
  for (int m = 0; m < 4; m++) {
#pragma unroll
    for (int n = 0; n < 4; n++) {
      const int c = bn + wc * 64 + n * 16 + l15;
      const float bs = bias[c];
      const int r0 = bm + wr * 64 + m * 16 + lg * 4;
      float vv[4];
#pragma unroll
      for (int reg = 0; reg < 4; reg++) vv[reg] = (float)acc[m][n][reg] * s + bs;
      const int which = c >> 10, hd = c & 1023;   // uniform over the 16-col fragment
      if (which < 2) {
        const float qs = (which == 0) ? CSC : 1.0f;   // fold softmax scale into Q
#pragma unroll
        for (int reg = 0; reg < 4; reg++) {
          const int r = r0 + reg;
          const int b = r >> 11, t = r & 2047;
          qkv_out[(size_t)which * (32u * 2048 * 64) +
                  (size_t)((((b << 4) + (hd >> 6)) * 2048 + t) << 6) + (hd & 63)] =
              (bf16_t)(vv[reg] * qs);
        }
      } else {
        // V^T [BH][D=64][T=2048], t contiguous within the 4 regs -> vector store
        const int b = r0 >> 11, t0 = r0 & 2047;
        const int h = hd >> 6, d = hd & 63;
        bf16x4 pk;
#pragma unroll
        for (int reg = 0; reg < 4; reg++) pk[reg] = (bf16_t)vv[reg];
        *(bf16x4*)(vt_out + ((size_t)((b << 4) + h) * 64 + d) * 2048 + t0) = pk;
      }
    }
  }
}

// ---------------- int8 GEMM (proj): 64x128 tile -> 512 blocks = 2 blocks/CU ----------------
// out[M=4096, N=1024] fp32; wave (wr=w>>1, wc=w&1) owns 32x64. 2/CU gives the 2-phase
// pipeline a partner block to overlap its per-K-step barrier drain with (R13's 128x128
// grid = 256 = 1/CU had none). Kernel body identical to R12's validated gemm_proj.
__global__ __launch_bounds__(256) void gemm_proj_kernel(
    const int8_t* __restrict__ A, const int8_t* __restrict__ Bw,
    const float* __restrict__ amaxA, const float* __restrict__ amaxB,
    const float* __restrict__ bias, float* __restrict__ f_out) {
  constexpr int K = 1024;
  __shared__ int8_t As[2][4096];
  __shared__ int8_t Bs[2][8192];
  const int tid = threadIdx.x;
  const int lane = tid & 63;
  const int w = tid >> 6, wr = w >> 1, wc = w & 1;
  const int l15 = lane & 15, lg = lane >> 4;
  const int bm = blockIdx.y * 64, bn = blockIdx.x * 128;

  const int sr = tid >> 2;
  const int sc = (tid & 3) * 16;
  const int8_t* gA = A + (size_t)(bm + sr) * K + sc;
  const int8_t* gB = Bw + (size_t)(bn + sr) * K + sc;

  auto stage = [&](int k0, int buf) {
    gl16(gA + k0, As[buf] + tid * 16);
    gl16(gB + k0, Bs[buf] + tid * 16);
    gl16(gB + 64 * K + k0, Bs[buf] + 4096 + tid * 16);
  };

  i32x4 acc[2][4] = {};

  stage(0, 0);
  __syncthreads();
  for (int ks = 0; ks < K / 64; ks++) {
    const int buf = ks & 1;
    if (ks + 1 < K / 64) stage((ks + 1) * 64, buf ^ 1);
    i32x4 aF[2], bF[4];
#pragma unroll
    for (int m = 0; m < 2; m++)
      aF[m] = *(const i32x4*)(As[buf] + (wr * 32 + m * 16 + l15) * 64 + lg * 16);
#pragma unroll
    for (int n = 0; n < 4; n++)
      bF[n] = *(const i32x4*)(Bs[buf] + (wc * 64 + n * 16 + l15) * 64 + lg * 16);
#pragma unroll
    for (int m = 0; m < 2; m++)
#pragma unroll
      for (int n = 0; n < 4; n++)
        acc[m][n] = __builtin_amdgcn_mfma_i32_16x16x64_i8(aF[m], bF[n], acc[m][n], 0, 0, 0);
    __syncthreads();
  }

  const float sA = fmaxf(amaxA[0] / QMAXF, 1e-8f);
  const float sB = fmaxf(amaxB[0] / QMAXF, 1e-8f);
  const float s = sA * sB;

#pragma unroll
  for (int m = 0; m < 2; m++) {
#pragma unroll
    for (int n = 0; n < 4; n++) {
      const int c = bn + wc * 64 + n * 16 + l15;
      const float bs = bias[c];
      const int r0 = bm + wr * 32 + m * 16 + lg * 4;
#pragma unroll
      for (int reg = 0; reg < 4; reg++)
        f_out[(size_t)(r0 + reg) * 1024 + c] = (float)acc[m][n][reg] * s + bs;
    }
  }
}

// ---------------- causal flash attention (R8 structure, best measured: 57.3 us) ----------------
// grid (32 bh, 16 pairs), block 256 = 4 waves x 16 q-rows (64-row supertile).
// Block handles supertiles {S, 31-S} sequentially: EVERY block exactly 33 KV-iters.
// Counted-vmcnt triple-buffer: no vmcnt(0) drain in main loop.
// Exact R8 ordering (load-bearing, verified by R9 A/B): barrier -> read kF -> read vB ->
// stage(it+2) -> lgkmcnt(0) fence -> QK MFMA.
// ZERO-MAX softmax (log2 domain, Q pre-scaled by CSC): p = exp2(a), no running max,
// no cross-lane ops in loop; deferred row-sum. Output bf16.
// Survived 7 perturbation classes (occupancy, sync geometry, memory path, tile size,
// amortization) — converged local optimum.
__global__ __launch_bounds__(256, 2) void attn_kernel(
    const bf16_t* __restrict__ Qg, const bf16_t* __restrict__ Kg, const bf16_t* __restrict__ VTg,
    bf16_t* __restrict__ Out, float* __restrict__ amax_out) {
  const int bh = blockIdx.x;            // fastest-varying -> bh%8 pins XCD (L2 locality)
  const int pairi = blockIdx.y;         // 0..15
  const int tid = threadIdx.x, lane = tid & 63, w = tid >> 6;
  const int l15 = lane & 15, lg = lane >> 4;
  const int b = bh >> 4, h = bh & 15;

  const bf16_t* Qp = Qg + (size_t)bh * 2048 * 64;
  const char* Kbase = (const char*)(Kg + (size_t)bh * 2048 * 64);
  const char* Vbase = (const char*)(VTg + (size_t)bh * 64 * 2048);

  __shared__ __align__(16) bf16_t Kb[3][4096];   // [64 kv][64 d], swizzled, triple-buffered
  __shared__ __align__(16) bf16_t Vb[3][4096];   // [64 d][64 kv], swizzled, triple-buffered

  // waves 0,1 stage K (4x 1KB each); waves 2,3 stage V; swizzle via global source
  auto stage = [&](int kv0, int buf) {
#pragma unroll
    for (int i = 0; i < 4; i++) {
      const int o = ((w & 1) * 4 + i) * 1024 + lane * 16;
      const int row = o >> 7;
      const int sbc = (o & 127) ^ ((row & 7) << 4);
      if (w < 2)
        gl16(Kbase + (size_t)(kv0 + row) * 128 + sbc, (char*)Kb[buf] + o);
      else
        gl16(Vbase + (size_t)row * 4096 + (size_t)kv0 * 2 + sbc, (char*)Vb[buf] + o);
    }
  };

  float am = 0.f;
  for (int half = 0; half < 2; ++half) {
    const int S = half ? (31 - pairi) : pairi;
    const int qb = S * 64 + w * 16;     // this wave's 16 q-rows
    const int nt = S + 1;
    const int qrow = qb + l15;

    bf16x8 qf[2];
#pragma unroll
    for (int ks = 0; ks < 2; ks++)
      qf[ks] = *(const bf16x8*)(Qp + (size_t)(qb + l15) * 64 + ks * 32 + lg * 8);

    f32x4 acc[4] = {};
    float lsum = 0.f;

    stage(0, 0);
    if (nt > 1) stage(64, 1);

    for (int it = 0; it < nt; ++it) {
      const int sl = it % 3;
      const int kv0 = it * 64;

      // own tile-it landed (tile it+1 stays in flight) -> barrier publishes all deposits
      if (it + 1 < nt) { asm volatile("s_waitcnt vmcnt(4)" ::: "memory"); }
      else             { asm volatile("s_waitcnt vmcnt(0)" ::: "memory"); }
      __builtin_amdgcn_sched_barrier(0);
      __builtin_amdgcn_s_barrier();      // raw: no drain, prefetches keep flying
      __builtin_amdgcn_sched_barrier(0);

      bf16x8 kF[4][2];
#pragma unroll
      for (int rf = 0; rf < 4; rf++)
#pragma unroll
        for (int ks = 0; ks < 2; ks++) {
          const int row = rf * 16 + l15;
          kF[rf][ks] = *(const bf16x8*)((const char*)Kb[sl] + row * 128 +
                                        ((ks * 64 + lg * 16) ^ ((row & 7) << 4)));
        }
      s16x4 vB[4][4];
#pragma unroll
      for (int cf = 0; cf < 4; cf++)
#pragma unroll
        for (int rf = 0; rf < 4; rf++) {
          const int row = cf * 16 + l15;
          vB[cf][rf] = *(const s16x4*)((const char*)Vb[sl] + row * 128 +
                                       ((rf * 32 + lg * 8) ^ ((row & 7) << 4)));
        }
      // prefetch tile it+2 into slot (it+2)%3 (readers of it-1 already past barrier(it))
      if (it + 2 < nt) stage(kv0 + 128, (it + 2) % 3);
      // fragments in VGPRs before compute
      asm volatile("s_waitcnt lgkmcnt(0)" ::: "memory");
      __builtin_amdgcn_sched_barrier(0);

      f32x4 sfT[4] = {};
      __builtin_amdgcn_s_setprio(1);
#pragma unroll
      for (int rf = 0; rf < 4; rf++)
#pragma unroll
        for (int ks = 0; ks < 2; ks++)
          sfT[rf] = __builtin_amdgcn_mfma_f32_16x16x32_bf16(kF[rf][ks], qf[ks], sfT[rf], 0, 0, 0);
      __builtin_amdgcn_s_setprio(0);

      // zero-max softmax (log2 domain; Q pre-scaled): p = exp2(a), no cross-lane ops
      const bool need_mask = (it == nt - 1);
      float p[16];
#pragma unroll
      for (int rf = 0; rf < 4; rf++)
#pragma unroll
        for (int reg = 0; reg < 4; reg++) {
          float v = sfT[rf][reg];
          if (need_mask && (kv0 + rf * 16 + lg * 4 + reg > qrow)) v = -1e30f;
          p[rf * 4 + reg] = __builtin_amdgcn_exp2f(v);
        }
      // tree-sum of own 16 p's -> per-lane partial (cross-lane deferred to epilogue)
      float s01 = (p[0] + p[1]) + (p[2] + p[3]);
      float s23 = (p[4] + p[5]) + (p[6] + p[7]);
      float s45 = (p[8] + p[9]) + (p[10] + p[11]);
      float s67 = (p[12] + p[13]) + (p[14] + p[15]);
      lsum += (s01 + s23) + (s45 + s67);

      // p -> bf16 A-frags, feed PV directly (no LDS roundtrip)
      s16x4 pa[4];
#pragma unroll
      for (int rf = 0; rf < 4; rf++) {
        bf16x4 t;
#pragma unroll
        for (int reg = 0; reg < 4; reg++) t[reg] = (bf16_t)p[rf * 4 + reg];
        pa[rf] = __builtin_bit_cast(s16x4, t);
      }
      __builtin_amdgcn_s_setprio(1);
#pragma unroll
      for (int cf = 0; cf < 4; cf++)
#pragma unroll
        for (int rf = 0; rf < 4; rf++)
          acc[cf] = __builtin_amdgcn_mfma_f32_16x16x16bf16_1k(pa[rf], vB[cf][rf], acc[cf], 0, 0, 0);
      __builtin_amdgcn_s_setprio(0);
    }

    // row-sum: lane l15 holds partial for row qb+l15; reduce across lg groups
    lsum += __shfl_xor(lsum, 16);
    lsum += __shfl_xor(lsum, 32);
    const float inv = 1.0f / lsum;
    float iq[4];
#pragma unroll
    for (int reg = 0; reg < 4; reg++) iq[reg] = __shfl(inv, lg * 4 + reg);
#pragma unroll
    for (int cf = 0; cf < 4; cf++)
#pragma unroll
      for (int reg = 0; reg < 4; reg++) {
        const float v = acc[cf][reg] * iq[reg];
        am = fmaxf(am, fabsf(v));
        const int t = qb + lg * 4 + reg;
        Out[(size_t)(b * 2048 + t) * 1024 + h * 64 + cf * 16 + l15] = (bf16_t)v;
      }

    __syncthreads();   // full drain: protect buffer slots across the half boundary
  }

#pragma unroll
  for (int dd = 1; dd < 64; dd <<= 1) am = fmaxf(am, __shfl_xor(am, dd));
  if (lane == 0) atomicMax((int*)amax_out, __float_as_int(am));
}

// ---------------- host ----------------
extern "C" void kernel_launch(void* const* d_in, const int* in_sizes, int n_in,
                              void* d_out, int out_size, void* d_ws, size_t ws_size,
                              hipStream_t stream) {
  const float* x = (const float*)d_in[0];
  const float* Wqkv = (const float*)d_in[1];
  const float* bqkv = (const float*)d_in[2];
  const float* Wproj = (const float*)d_in[3];
  const float* bproj = (const float*)d_in[4];
  float* out = (float*)d_out;

  char* ws = (char*)d_ws;
  float* amax = (float*)ws;                                  // 4 floats
  int8_t* xq = (int8_t*)(ws + 256);                          // 4 MB
  int8_t* wqq = xq + (size_t)4096 * 1024;                    // 3 MB
  int8_t* wpq = wqq + (size_t)3072 * 1024;                   // 1 MB
  bf16_t* qkv = (bf16_t*)(ws + 8388864);                     // Q | K | VT, 3 x 8 MB bf16
  bf16_t* Q = qkv;
  bf16_t* Kk = qkv + (size_t)32 * 2048 * 64;
  bf16_t* VT = qkv + (size_t)2 * 32 * 2048 * 64;             // [BH][D][T]
  bf16_t* aout = (bf16_t*)(ws + 33554688);                   // 8 MB bf16 attn out
  int8_t* outq = (int8_t*)(ws + 50331904);                   // 4 MB

  hipMemsetAsync(amax, 0, 16, stream);
  amax3_kernel<<<896, 256, 0, stream>>>(x, 4194304, Wqkv, 3145728, Wproj, 1048576, amax);
  quant3_kernel<<<896, 256, 0, stream>>>(x, 4194304, Wqkv, 3145728, Wproj, 1048576, amax,
                                         xq, wqq, wpq);
  gemm_qkv_kernel<<<dim3(24, 32), 256, 0, stream>>>(xq, wqq, amax + 0, amax + 1, bqkv,
                                                    qkv, VT);
  attn_kernel<<<dim3(32, 16), 256, 0, stream>>>(Q, Kk, VT, aout, amax + 3);
  quant_bf16_kernel<<<512, 256, 0, stream>>>((const u32*)aout, 4194304, amax + 3, outq);
  gemm_proj_kernel<<<dim3(8, 64), 256, 0, stream>>>(outq, wpq, amax + 3, amax + 2, bproj, out);
}